// Round 3
// baseline (126.952 us; speedup 1.0000x reference)
//
#include <hip/hip_runtime.h>
#include <hip/hip_bf16.h>
#include <math.h>

#define N_NODES 1024
#define T_DIM 8

typedef __bf16 bf16x8 __attribute__((ext_vector_type(8)));
typedef float  f32x4  __attribute__((ext_vector_type(4)));

__device__ __forceinline__ float readlane_f(float v, int l) {
    return __uint_as_float(__builtin_amdgcn_readlane(__float_as_uint(v), l));
}
__device__ __forceinline__ float firstlane_f(float v) {
    return __uint_as_float(__builtin_amdgcn_readfirstlane(__float_as_uint(v)));
}

// ---- Kernel A: h = inp@W ; s1,s2 ; hF = (h*mask_j) in B-frag-ordered tiles --
// hF tile (bt,jt) = 8 chunks of 1KB; chunk c=kc*4+nc, lane l, m 0..7 holds
// h[o = nc*16 + (l&15)][j = jt*64 + (l>>4)*8 + kc*32 + m] * mask_j.
// mask_j folded here (hF only feeds PV; softmax denominator is unmasked).
__global__ __launch_bounds__(256) void gat_h_kernel(
    const float* __restrict__ inp, const float* __restrict__ W,
    const float* __restrict__ a, const float* __restrict__ att_mask,
    __bf16* __restrict__ hF, float* __restrict__ s1w, float* __restrict__ s2w)
{
    __shared__ float Wl[64 * 64];
    __shared__ float xl[64 * 64];
    __shared__ __bf16 htl[64 * 72];   // [o][j], stride 72

    const int tid  = threadIdx.x;
    const int blk  = blockIdx.x;
    const int t    = blk & 7;         // XCD id
    const int r_   = blk >> 3;        // 0..63
    const int b    = r_ & 3;
    const int nt   = r_ >> 2;         // j-tile 0..15
    const int bt   = b * 8 + t;
    const int n0   = nt * 64;
    const int lane = tid & 63;        // = o in compute phase
    const int wave = tid >> 6;

    const float4* W4  = (const float4*)W;
    float4*       Wl4 = (float4*)Wl;
    const float4* x4  = (const float4*)(inp + (size_t)(bt * N_NODES + n0) * 64);
    float4*       xl4 = (float4*)xl;
#pragma unroll
    for (int k = 0; k < 4; ++k) {
        Wl4[tid + k * 256] = W4[tid + k * 256];
        xl4[tid + k * 256] = x4[tid + k * 256];
    }
    const float a1 = a[lane];
    const float a2 = a[64 + lane];
    __syncthreads();

#pragma unroll 1
    for (int rg = 0; rg < 16; rg += 4) {
        float xr[4], acc[4];
#pragma unroll
        for (int q = 0; q < 4; ++q) {
            xr[q]  = xl[(wave * 16 + rg + q) * 64 + lane];
            acc[q] = 0.f;
        }
#pragma unroll
        for (int f = 0; f < 64; ++f) {
            float w = Wl[f * 64 + lane];
#pragma unroll
            for (int q = 0; q < 4; ++q)
                acc[q] = fmaf(readlane_f(xr[q], f), w, acc[q]);
        }
#pragma unroll
        for (int q = 0; q < 4; ++q) {
            const int r = wave * 16 + rg + q;   // local j
            float v1 = acc[q] * a1, v2 = acc[q] * a2;
#pragma unroll
            for (int off = 32; off; off >>= 1) {
                v1 += __shfl_xor(v1, off, 64);
                v2 += __shfl_xor(v2, off, 64);
            }
            if (lane == 0) {
                s1w[bt * N_NODES + n0 + r] = v1;
                s2w[bt * N_NODES + n0 + r] = v2;
            }
            const float mjr = att_mask[((size_t)b * N_NODES + n0 + r) * T_DIM + t];
            htl[lane * 72 + r] = (__bf16)(acc[q] * mjr);   // [o][j]
        }
    }
    __syncthreads();

    // hF write: B-frag-ordered chunks (validated r10-r13)
    {
        const int l  = tid & 63;
        const int w  = tid >> 6;
        __bf16* tbase = hF + (size_t)(bt * 16 + nt) * 4096;
#pragma unroll
        for (int cc = 0; cc < 2; ++cc) {
            const int c  = w + cc * 4;       // chunk = kc*4 + nc
            const int nc = c & 3;
            const int kc = c >> 2;
            bf16x8 v = *(const bf16x8*)&htl[(nc * 16 + (l & 15)) * 72
                                            + (l >> 4) * 8 + kc * 32];
            *(bf16x8*)(tbase + (c * 64 + l) * 8) = v;
        }
    }
}

// ---- Kernel B: flash GAT — j-split 2-way for occupancy -----------------------
// 2048 blocks x 128 thr (2 waves). Wave w handles j-tiles w*8 .. w*8+7 of its
// itile; partial acc/lsum combined via LDS + one barrier at the end.
// 4096 waves total; __launch_bounds__(128,3) caps VGPR at 170 -> 3 waves/SIMD
// (was 2, grid-limited). Body slimmed to fit: h loaded in-iteration (no reg
// prefetch -- R1/R2 proved h cache level is irrelevant), adj 1-deep pipeline,
// s1 hoisted to SGPR via readfirstlane (wave-uniform values).
// XCD remap kept: XCD = blk%8 = t. P via wave-private LDS slice, no in-loop
// shuffles or barriers.
__global__ __launch_bounds__(128, 3) void gat_attn_kernel(
    const float* __restrict__ adj, const float* __restrict__ att_mask,
    const __bf16* __restrict__ hF, const float* __restrict__ s1w,
    const float* __restrict__ s2w, float* __restrict__ out)
{
    __shared__ __align__(16) __bf16 p_l[2][16 * 72];   // per-wave [row][j], pad 72
    __shared__ __align__(16) float  cacc[64 * 16];     // wave1 acc dump
    __shared__ float clsum[16];                        // wave1 lsum dump

    const int blk   = blockIdx.x;       // 0..2047
    const int t     = blk & 7;          // XCD id
    const int r_    = blk >> 3;         // 0..255
    const int b     = r_ & 3;
    const int itile = r_ >> 2;          // 0..63
    const int bt    = b * 8 + t;
    const int irow0 = itile * 16;
    const int wave  = threadIdx.x >> 6; // 0,1 = j-half
    const int lane  = threadIdx.x & 63; // = j within tile (score phase)
    const int l15   = lane & 15;
    const int quad  = lane >> 4;
    const int jt0   = wave * 8;         // first j-tile of this wave's half

    f32x4 acc[4];
#pragma unroll
    for (int nc = 0; nc < 4; ++nc) acc[nc] = (f32x4){0.f, 0.f, 0.f, 0.f};
    float lsum[16], s1v[16];
#pragma unroll
    for (int r = 0; r < 16; ++r) {
        lsum[r] = 0.f;
        s1v[r]  = firstlane_f(s1w[bt * N_NODES + irow0 + r]);   // SGPR-resident
    }

    const float*  adjrow = adj + (size_t)t * N_NODES * N_NODES
                               + (size_t)irow0 * N_NODES + lane;
    const __bf16* htb    = hF + (size_t)bt * 16 * 4096 + lane * 8;
    const float*  s2bt   = s2w + bt * N_NODES;
    __bf16* pwr = &p_l[wave][0] + lane;                      // score write (lane = j)
    const __bf16* prd = &p_l[wave][0] + l15 * 72 + quad * 8; // P A-frag read

    // ---- preload: adj + s2 for first tile of this wave's half ----
    float adj0[16];
    float s2c;
    {
#pragma unroll
        for (int r = 0; r < 16; ++r)
            adj0[r] = adjrow[(size_t)r * N_NODES + jt0 * 64];
        s2c = s2bt[jt0 * 64 + lane];
    }

#pragma unroll 2
    for (int it = 0; it < 8; ++it) {
        const int jc = jt0 + it;                // current tile
        const int jn = jt0 + ((it + 1) & 7);    // next tile (wraps harmlessly)

        // ---- prefetch adj/s2 1 ahead ----
        float adjn[16];
#pragma unroll
        for (int r = 0; r < 16; ++r)
            adjn[r] = adjrow[(size_t)r * N_NODES + jn * 64];
        const float s2n = s2bt[jn * 64 + lane];

        // ---- h for current tile: issued early, consumed by MFMA at end ----
        bf16x8 hc[8];
        const __bf16* hp = htb + (size_t)jc * 4096;
#pragma unroll
        for (int c = 0; c < 8; ++c) hc[c] = *(const bf16x8*)(hp + c * 512);

        // ---- scores for current tile (lane = j); leaky bounds e*adj in
        // [-6,~16] so exp never overflows -> no max pass needed ----
#pragma unroll
        for (int r = 0; r < 16; ++r) {
            float e = s1v[r] + s2c;
            e = fmaxf(e, 0.2f * e);
            float p = (adj0[r] > 0.f) ? __expf(e * adj0[r]) : 0.f;
            lsum[r] += p;
            pwr[r * 72] = (__bf16)p;
        }

        // ---- P -> A-frag via wave-private LDS, then 8 MFMAs ----
        bf16x8 af0 = *(const bf16x8*)(prd);
        bf16x8 af1 = *(const bf16x8*)(prd + 32);
#pragma unroll
        for (int nc = 0; nc < 4; ++nc)
            acc[nc] = __builtin_amdgcn_mfma_f32_16x16x32_bf16(af0, hc[nc], acc[nc], 0, 0, 0);
#pragma unroll
        for (int nc = 0; nc < 4; ++nc)
            acc[nc] = __builtin_amdgcn_mfma_f32_16x16x32_bf16(af1, hc[4 + nc], acc[nc], 0, 0, 0);

        // ---- shift adj/s2 pipeline ----
#pragma unroll
        for (int r = 0; r < 16; ++r) adj0[r] = adjn[r];
        s2c = s2n;
    }

    // ---- reduce lsum across lanes (both waves) ----
#pragma unroll
    for (int r = 0; r < 16; ++r) {
#pragma unroll
        for (int off = 32; off; off >>= 1)
            lsum[r] += __shfl_xor(lsum[r], off, 64);
    }

    // ---- combine the two j-halves via LDS ----
    if (wave == 1) {
        float* cb = cacc + lane * 16;
#pragma unroll
        for (int nc = 0; nc < 4; ++nc)
#pragma unroll
            for (int reg = 0; reg < 4; ++reg)
                cb[nc * 4 + reg] = acc[nc][reg];
        if (lane == 0) {
#pragma unroll
            for (int r = 0; r < 16; ++r) clsum[r] = lsum[r];
        }
    }
    __syncthreads();
    if (wave == 0) {
        const float* cb = cacc + lane * 16;
#pragma unroll
        for (int nc = 0; nc < 4; ++nc)
#pragma unroll
            for (int reg = 0; reg < 4; ++reg)
                acc[nc][reg] += cb[nc * 4 + reg];
#pragma unroll
        for (int r = 0; r < 16; ++r) lsum[r] += clsum[r];

        // ---- epilogue: mi/ls scale + ELU + store ----
#pragma unroll
        for (int reg = 0; reg < 4; ++reg) {
            float ls = (quad == 0) ? lsum[reg] : (quad == 1) ? lsum[4 + reg]
                     : (quad == 2) ? lsum[8 + reg] : lsum[12 + reg];
            const int i = irow0 + quad * 4 + reg;
            float mi    = att_mask[((size_t)b * N_NODES + i) * T_DIM + t];
            float scale = mi / ls;
#pragma unroll
            for (int nc = 0; nc < 4; ++nc) {
                float v = acc[nc][reg] * scale;
                v = (v > 0.f) ? v : (__expf(v) - 1.f);
                out[((size_t)bt * N_NODES + i) * 64 + nc * 16 + l15] = v;
            }
        }
    }
}

extern "C" void kernel_launch(void* const* d_in, const int* in_sizes, int n_in,
                              void* d_out, int out_size, void* d_ws, size_t ws_size,
                              hipStream_t stream) {
    (void)in_sizes; (void)n_in; (void)out_size; (void)ws_size;
    const float* adj      = (const float*)d_in[0];   // (T,N,N)
    const float* inp      = (const float*)d_in[1];   // (B,T,N,FI)
    const float* att_mask = (const float*)d_in[2];   // (B,N,T)
    const float* W        = (const float*)d_in[3];   // (FI,FO)
    const float* a        = (const float*)d_in[4];   // (2*FO,1)
    float* out = (float*)d_out;

    // ws: hF 4MB | s1 128KB | s2 128KB
    __bf16* hF  = (__bf16*)d_ws;
    float*  s1w = (float*)((char*)d_ws + (size_t)4 * 1024 * 1024);
    float*  s2w = s1w + 32 * N_NODES;

    gat_h_kernel<<<512, 256, 0, stream>>>(inp, W, a, att_mask, hF, s1w, s2w);
    gat_attn_kernel<<<2048, 128, 0, stream>>>(adj, att_mask, hF, s1w, s2w, out);
}